// Round 9
// baseline (60.983 us; speedup 1.0000x reference)
//
#include <hip/hip_runtime.h>

#define D 32
#define H 128
#define TN 256            // tanh table entries
#define TRANGE 6.0f       // table covers [-6, 6]

typedef float v2f __attribute__((ext_vector_type(2)));
typedef float v8f __attribute__((ext_vector_type(8)));

// ---------------- Stage A: metric + folded per-batch constants ----------------
// grid = 256: blk = (b, q); q = m-chunk of 128 metric outputs. h1 recomputed
// redundantly per block. cpk8[b][h] = {u-base, S*a1, S*a2, S*a3, cw2, 0,0,0}
// (32 B, one s_load_dwordx8 in the hot loop), u = S*x + TN/2.
__global__ __launch_bounds__(256) void setup_kernel(
    const float* __restrict__ points,
    const float* __restrict__ mw1, const float* __restrict__ mb1,
    const float* __restrict__ mw2, const float* __restrict__ mb2,
    const float* __restrict__ cw1, const float* __restrict__ cb1,
    const float* __restrict__ cw2,
    const float* __restrict__ rw1, const float* __restrict__ rb1,
    float* __restrict__ metric, v8f* __restrict__ cpk8,
    float* __restrict__ rbase)
{
    __shared__ float p[D];
    __shared__ float h1[H];
    const int blk = blockIdx.x;
    const int b   = blk >> 3;
    const int q   = blk & 7;
    const int t   = threadIdx.x;
    if (t < D) p[t] = points[b * D + t];
    __syncthreads();

    if (t < H) {
        float acc = mb1[t];
        #pragma unroll
        for (int d = 0; d < D; ++d) acc = fmaf(p[d], mw1[d * H + t], acc);
        h1[t] = fmaxf(acc, 0.0f);
    }

    if (q == 0 && t < H) {
        constexpr float S = (float)TN / (2.0f * TRANGE);   // 21.3333
        float cacc = cb1[t];
        #pragma unroll
        for (int d = 0; d < D; ++d) cacc = fmaf(p[d], cw1[d * H + t], cacc);
        v8f c;
        c[0] = S * cacc + (float)(TN / 2);
        c[1] = S * cw1[32 * H + t];
        c[2] = S * cw1[33 * H + t];
        c[3] = S * cw1[34 * H + t];
        c[4] = cw2[t];
        c[5] = 0.0f; c[6] = 0.0f; c[7] = 0.0f;
        cpk8[b * H + t] = c;
    }
    if (q == 1) {
        float racc = rb1[t];
        #pragma unroll
        for (int d = 0; d < D; ++d) racc = fmaf(p[d], rw1[d * 256 + t], racc);
        rbase[b * 256 + t] = racc;
    }
    __syncthreads();

    if (t < 128) {
        const int m = q * 128 + t;
        float acc = mb2[m];
        #pragma unroll 8
        for (int h = 0; h < H; ++h) acc = fmaf(h1[h], mw2[h * 1024 + m], acc);
        metric[b * 1024 + m] = acc;
    }
}

// ---------------- Stage B: christoffel, 1M rows ----------------
// Uniform-request diet: ONE s_load_dwordx8 per h-iter (all 5 constants packed),
// amortized over 4 rows/thread -> 2048 requests/CU (was 8192).
// tanh via 256-entry LDS {value,slope} table (2 KB), 1 ds_read_b64 gather/eval.
// grid = 32*32 = 1024 blocks (b, i), block = 256, 4 adjacent k per thread.
__global__ __launch_bounds__(256) void christoffel_kernel(
    const float* __restrict__ metric,
    const v8f* __restrict__ cpk8, const float* __restrict__ cb2,
    float* __restrict__ gamma)
{
    __shared__ float2 tab[TN];          // 2 KB
    const int blk = blockIdx.x;
    const int b   = blk >> 5;
    const int i   = blk & 31;
    const int t   = threadIdx.x;

    // one-time table fill: 1 entry per thread
    constexpr float hstep = 2.0f * TRANGE / (float)TN;
    constexpr float Kc = 2.8853900817779268f;   // 2*log2(e)
    if (t < TN) {
        const float x0 = -TRANGE + t * hstep;
        const float e0 = __builtin_amdgcn_exp2f(Kc * x0);
        const float v0 = 1.0f - 2.0f * __builtin_amdgcn_rcpf(e0 + 1.0f);
        const float e1 = __builtin_amdgcn_exp2f(Kc * (x0 + hstep));
        const float v1 = 1.0f - 2.0f * __builtin_amdgcn_rcpf(e1 + 1.0f);
        tab[t] = make_float2(v0, v1 - v0);
    }

    // per-thread metric values straight from L2 (no LDS staging)
    const int r0 = t * 4;               // row within (b,i): r = j*32 + k
    const int j  = r0 >> 5;
    const int k0 = r0 & 31;             // multiple of 4
    const float* __restrict__ Mb = metric + b * 1024;
    const float gij = Mb[i * 32 + j];
    float gjk[4], gki[4], acc[4];
    #pragma unroll
    for (int r = 0; r < 4; ++r) {
        gjk[r] = Mb[j * 32 + k0 + r];
        gki[r] = Mb[(k0 + r) * 32 + i];
        acc[r] = 0.0f;
    }
    __syncthreads();

    const v8f* __restrict__ cp = cpk8 + b * H;  // wave-uniform stream

    #pragma unroll 4
    for (int h = 0; h < H; ++h) {
        const v8f c = cp[h];            // ONE s_load_dwordx8
        const float pre = fmaf(gij, c[1], c[0]);
        #pragma unroll
        for (int r = 0; r < 4; ++r) {
            float u = fmaf(gki[r], c[3], fmaf(gjk[r], c[2], pre));
            u = __builtin_amdgcn_fmed3f(u, 0.0f, (float)(TN - 1));
            const int   iu = (int)u;
            const float fr = u - (float)iu;
            const float2 pv = tab[iu];  // ds_read_b64 gather
            acc[r] = fmaf(fmaf(fr, pv.y, pv.x), c[4], acc[r]);
        }
    }

    const float bias = cb2[0];
    float4 res = make_float4(acc[0] + bias, acc[1] + bias, acc[2] + bias, acc[3] + bias);
    *((float4*)(gamma + ((b * 32 + i) * 32 + j) * 32 + k0)) = res;
}

// ---------------- Stage C: ricci ----------------
// Block = (b,i,jhalf): 16 outputs. Thread = hidden unit h; 33 weights in VGPRs.
// Gamma rows wave-uniform, read as float8 -> s_load_dwordx8 (4 requests per jj,
// was 8). Paired shuffle reduction. grid = 2048, block = 256.
__global__ __launch_bounds__(256) void ricci_kernel(
    const float* __restrict__ metric, const float* __restrict__ rbase,
    const float* __restrict__ rw1, const float* __restrict__ rw2,
    const float* __restrict__ rb2,
    const float* __restrict__ gamma,
    float* __restrict__ out)
{
    __shared__ float red[4][16];
    const int blk = blockIdx.x;
    const int bi  = blk >> 1;           // (b,i)
    const int b   = blk >> 6;
    const int i   = (blk >> 1) & 31;
    const int jh  = blk & 1;
    const int t   = threadIdx.x;

    float w[33];
    #pragma unroll
    for (int f = 0; f < 33; ++f) w[f] = rw1[(32 + f) * 256 + t];
    const float rbv   = rbase[b * 256 + t];
    const float wo    = rw2[t];
    const float rbias = rb2[0];

    const v8f*   __restrict__ G8   = (const v8f*)(gamma + bi * 1024 + jh * 512);
    const float* __restrict__ Mrow = metric + b * 1024 + i * 32 + jh * 16;

    const int wid  = t >> 6;
    const int lane = t & 63;

    #pragma unroll 2
    for (int jp = 0; jp < 8; ++jp) {
        float pp[2];
        #pragma unroll
        for (int s = 0; s < 2; ++s) {
            const int jj = jp * 2 + s;
            float hid = fmaf(Mrow[jj], w[0], rbv);
            #pragma unroll
            for (int k8 = 0; k8 < 4; ++k8) {
                const v8f g = G8[jj * 4 + k8];      // s_load_dwordx8
                #pragma unroll
                for (int e = 0; e < 8; ++e)
                    hid = fmaf(g[e], w[k8 * 8 + e + 1], hid);
            }
            pp[s] = fmaxf(hid, 0.0f) * wo;
        }
        const float t0 = pp[0] + __shfl_xor(pp[0], 1);
        const float t1 = pp[1] + __shfl_xor(pp[1], 1);
        float z = (lane & 1) ? t1 : t0;
        #pragma unroll
        for (int off = 2; off < 64; off <<= 1) z += __shfl_xor(z, off);
        if (lane < 2) red[wid][jp * 2 + lane] = z;
    }
    __syncthreads();
    if (t < 16) out[bi * 32 + jh * 16 + t] = red[0][t] + red[1][t] + red[2][t] + red[3][t] + rbias;
}

extern "C" void kernel_launch(void* const* d_in, const int* in_sizes, int n_in,
                              void* d_out, int out_size, void* d_ws, size_t ws_size,
                              hipStream_t stream) {
    const float* points = (const float*)d_in[0];
    const float* mw1 = (const float*)d_in[1];
    const float* mb1 = (const float*)d_in[2];
    const float* mw2 = (const float*)d_in[3];
    const float* mb2 = (const float*)d_in[4];
    const float* cw1 = (const float*)d_in[5];
    const float* cb1 = (const float*)d_in[6];
    const float* cw2 = (const float*)d_in[7];
    const float* cb2 = (const float*)d_in[8];
    const float* rw1 = (const float*)d_in[9];
    const float* rb1 = (const float*)d_in[10];
    const float* rw2 = (const float*)d_in[11];
    const float* rb2 = (const float*)d_in[12];
    float* out = (float*)d_out;

    char* ws = (char*)d_ws;
    float* metric = (float*)(ws);                  // 32*1024 f32 = 128 KB @ 0
    v8f*   cpk8   = (v8f*)(ws + 131072);           // 32*128 * 32 B = 128 KB
    float* rbase  = (float*)(ws + 262144);         // 32*256 f32 = 32 KB
    float* gamma  = (float*)(ws + 294912);         // 32*32768 f32 = 4 MB

    setup_kernel<<<256, 256, 0, stream>>>(points, mw1, mb1, mw2, mb2,
                                          cw1, cb1, cw2, rw1, rb1,
                                          metric, cpk8, rbase);
    christoffel_kernel<<<1024, 256, 0, stream>>>(metric, cpk8, cb2, gamma);
    ricci_kernel<<<2048, 256, 0, stream>>>(metric, rbase, rw1, rw2, rb2, gamma, out);
}

// Round 10
// 55.297 us; speedup vs baseline: 1.1028x; 1.1028x over previous
//
#include <hip/hip_runtime.h>

#define D 32
#define H 128
#define TN 256            // tanh table entries
#define TRANGE 6.0f       // table covers [-6, 6]

typedef float v2f __attribute__((ext_vector_type(2)));
typedef float v8f __attribute__((ext_vector_type(8)));

// ---------------- Stage A: metric + folded per-batch constants ----------------
// grid = 256: blk = (b, q); q = m-chunk of 128 metric outputs.
// cpkT[b][hp] (even h=2hp, table path, u-space):  {S*cbase+128, S*a1, S*a2, S*a3, cw2, 0,0,0}
// cpkX[b][hp] (odd h=2hp+1, trans path, Kc-space):{Kc*cbase,  Kc*a1, Kc*a2, Kc*a3, -2*cw2, 0,0,0}
// cc = cb2 + sum_{odd h} cw2[h]   (trans-path tanh=1-2r contributes its +w here)
__global__ __launch_bounds__(256) void setup_kernel(
    const float* __restrict__ points,
    const float* __restrict__ mw1, const float* __restrict__ mb1,
    const float* __restrict__ mw2, const float* __restrict__ mb2,
    const float* __restrict__ cw1, const float* __restrict__ cb1,
    const float* __restrict__ cw2, const float* __restrict__ cb2,
    const float* __restrict__ rw1, const float* __restrict__ rb1,
    float* __restrict__ metric, v8f* __restrict__ cpkT, v8f* __restrict__ cpkX,
    float* __restrict__ rbase, float* __restrict__ cc)
{
    __shared__ float p[D];
    __shared__ float h1[H];
    const int blk = blockIdx.x;
    const int b   = blk >> 3;
    const int q   = blk & 7;
    const int t   = threadIdx.x;
    if (t < D) p[t] = points[b * D + t];
    __syncthreads();

    if (t < H) {
        float acc = mb1[t];
        #pragma unroll
        for (int d = 0; d < D; ++d) acc = fmaf(p[d], mw1[d * H + t], acc);
        h1[t] = fmaxf(acc, 0.0f);
    }

    if (q == 0 && t < H) {
        constexpr float S  = (float)TN / (2.0f * TRANGE);   // 21.3333
        constexpr float Kc = 2.8853900817779268f;           // 2*log2(e)
        const int h = t;
        float cacc = cb1[h];
        #pragma unroll
        for (int d = 0; d < D; ++d) cacc = fmaf(p[d], cw1[d * H + h], cacc);
        const float a1 = cw1[32 * H + h];
        const float a2 = cw1[33 * H + h];
        const float a3 = cw1[34 * H + h];
        const float w  = cw2[h];
        v8f c;
        if ((h & 1) == 0) {         // table path
            c[0] = S * cacc + (float)(TN / 2);
            c[1] = S * a1; c[2] = S * a2; c[3] = S * a3;
            c[4] = w; c[5] = 0.0f; c[6] = 0.0f; c[7] = 0.0f;
            cpkT[b * 64 + (h >> 1)] = c;
        } else {                    // trans path
            c[0] = Kc * cacc;
            c[1] = Kc * a1; c[2] = Kc * a2; c[3] = Kc * a3;
            c[4] = -2.0f * w; c[5] = 0.0f; c[6] = 0.0f; c[7] = 0.0f;
            cpkX[b * 64 + (h >> 1)] = c;
        }
    }
    if (q == 1) {
        float racc = rb1[t];
        #pragma unroll
        for (int d = 0; d < D; ++d) racc = fmaf(p[d], rw1[d * 256 + t], racc);
        rbase[b * 256 + t] = racc;
    }
    if (q == 2 && b == 0 && t < 64) {
        float v = cw2[2 * t + 1];   // odd-h weights
        #pragma unroll
        for (int off = 32; off > 0; off >>= 1) v += __shfl_xor(v, off);
        if (t == 0) cc[0] = v + cb2[0];
    }
    __syncthreads();

    if (t < 128) {
        const int m = q * 128 + t;
        float acc = mb2[m];
        #pragma unroll 8
        for (int h = 0; h < H; ++h) acc = fmaf(h1[h], mw2[h * 1024 + m], acc);
        metric[b * 1024 + m] = acc;
    }
}

// ---------------- Stage B: christoffel, 1M rows ----------------
// Pipe-balanced h-loop: even h via 256-entry LDS table (8 VALU + 1 ds_read_b64),
// odd h via exp2+rcp (4 VALU + 2 trans). Halves the pressure on each of the
// LDS and trans pipes vs single-path variants; VALU/trans/LDS all ~balanced.
// grid = 32*32*2 = 2048 blocks (b, i, j-half), block = 256, 2 rows/thread.
__global__ __launch_bounds__(256) void christoffel_kernel(
    const float* __restrict__ metric,
    const v8f* __restrict__ cpkT, const v8f* __restrict__ cpkX,
    const float* __restrict__ cc,
    float* __restrict__ gamma)
{
    __shared__ float2 tab[TN];          // 2 KB
    const int blk = blockIdx.x;
    const int b   = blk >> 6;
    const int i   = (blk >> 1) & 31;
    const int jh  = blk & 1;
    const int t   = threadIdx.x;

    // one-time table fill: 1 entry per thread
    constexpr float hstep = 2.0f * TRANGE / (float)TN;
    constexpr float Kc = 2.8853900817779268f;   // 2*log2(e)
    if (t < TN) {
        const float x0 = -TRANGE + t * hstep;
        const float e0 = __builtin_amdgcn_exp2f(Kc * x0);
        const float v0 = 1.0f - 2.0f * __builtin_amdgcn_rcpf(e0 + 1.0f);
        const float e1 = __builtin_amdgcn_exp2f(Kc * (x0 + hstep));
        const float v1 = 1.0f - 2.0f * __builtin_amdgcn_rcpf(e1 + 1.0f);
        tab[t] = make_float2(v0, v1 - v0);
    }

    const int j  = jh * 16 + (t >> 4);
    const int k0 = (t & 15) * 2;
    const float* __restrict__ Mb = metric + b * 1024;
    const float gij  = Mb[i * 32 + j];
    const float gjk0 = Mb[j * 32 + k0];
    const float gjk1 = Mb[j * 32 + k0 + 1];
    const float gki0 = Mb[k0 * 32 + i];
    const float gki1 = Mb[(k0 + 1) * 32 + i];
    __syncthreads();

    float acc0 = 0.0f, acc1 = 0.0f;
    const v8f* __restrict__ cpT = cpkT + b * 64;    // wave-uniform streams
    const v8f* __restrict__ cpX = cpkX + b * 64;

    #pragma unroll 4
    for (int hp = 0; hp < 64; ++hp) {
        const v8f ct = cpT[hp];
        const v8f cx = cpX[hp];
        // table path (even h)
        {
            const float pre = fmaf(gij, ct[1], ct[0]);
            float u0 = fmaf(gki0, ct[3], fmaf(gjk0, ct[2], pre));
            float u1 = fmaf(gki1, ct[3], fmaf(gjk1, ct[2], pre));
            u0 = __builtin_amdgcn_fmed3f(u0, 0.0f, (float)(TN - 1));
            u1 = __builtin_amdgcn_fmed3f(u1, 0.0f, (float)(TN - 1));
            const int   i0 = (int)u0;
            const int   i1 = (int)u1;
            const float fr0 = u0 - (float)i0;
            const float fr1 = u1 - (float)i1;
            const float2 p0 = tab[i0];  // ds_read_b64 gather
            const float2 p1 = tab[i1];
            acc0 = fmaf(fmaf(fr0, p0.y, p0.x), ct[4], acc0);
            acc1 = fmaf(fmaf(fr1, p1.y, p1.x), ct[4], acc1);
        }
        // trans path (odd h): acc += -2w * rcp(exp2(x)+1)   (+w folded into cc)
        {
            const float pre = fmaf(gij, cx[1], cx[0]);
            const float x0 = fmaf(gki0, cx[3], fmaf(gjk0, cx[2], pre));
            const float x1 = fmaf(gki1, cx[3], fmaf(gjk1, cx[2], pre));
            const float r0 = __builtin_amdgcn_rcpf(__builtin_amdgcn_exp2f(x0) + 1.0f);
            const float r1 = __builtin_amdgcn_rcpf(__builtin_amdgcn_exp2f(x1) + 1.0f);
            acc0 = fmaf(r0, cx[4], acc0);
            acc1 = fmaf(r1, cx[4], acc1);
        }
    }

    const float bias = cc[0];
    v2f res; res.x = acc0 + bias; res.y = acc1 + bias;
    *((v2f*)(gamma + ((b * 32 + i) * 32 + j) * 32 + k0)) = res;
}

// ---------------- Stage C: ricci (R7 form — best measured) ----------------
// Block = (b,i,jhalf): 16 outputs. Thread = hidden unit h; 33 weights in VGPRs.
// Gamma rows wave-uniform -> scalar float4 stream. Paired shuffle reduction.
// grid = 2048, block = 256
__global__ __launch_bounds__(256) void ricci_kernel(
    const float* __restrict__ metric, const float* __restrict__ rbase,
    const float* __restrict__ rw1, const float* __restrict__ rw2,
    const float* __restrict__ rb2,
    const float* __restrict__ gamma,
    float* __restrict__ out)
{
    __shared__ float red[4][16];
    const int blk = blockIdx.x;
    const int bi  = blk >> 1;           // (b,i)
    const int b   = blk >> 6;
    const int i   = (blk >> 1) & 31;
    const int jh  = blk & 1;
    const int t   = threadIdx.x;

    float w[33];
    #pragma unroll
    for (int f = 0; f < 33; ++f) w[f] = rw1[(32 + f) * 256 + t];
    const float rbv   = rbase[b * 256 + t];
    const float wo    = rw2[t];
    const float rbias = rb2[0];

    const float4* __restrict__ G4   = (const float4*)(gamma + bi * 1024 + jh * 512);
    const float*  __restrict__ Mrow = metric + b * 1024 + i * 32 + jh * 16;

    const int wid  = t >> 6;
    const int lane = t & 63;

    #pragma unroll 2
    for (int jp = 0; jp < 8; ++jp) {
        float pp[2];
        #pragma unroll
        for (int s = 0; s < 2; ++s) {
            const int jj = jp * 2 + s;
            v2f hA = (v2f)(0.0f), hB = (v2f)(0.0f);
            #pragma unroll
            for (int k4 = 0; k4 < 8; ++k4) {
                const float4 g = G4[jj * 8 + k4];   // uniform -> scalar load
                v2f glo; glo.x = g.x; glo.y = g.y;
                v2f ghi; ghi.x = g.z; ghi.y = g.w;
                v2f wlo; wlo.x = w[k4 * 4 + 1]; wlo.y = w[k4 * 4 + 2];
                v2f whi; whi.x = w[k4 * 4 + 3]; whi.y = w[k4 * 4 + 4];
                hA = glo * wlo + hA;
                hB = ghi * whi + hB;
            }
            const float hid = fmaf(Mrow[jj], w[0], rbv) + (hA.x + hA.y) + (hB.x + hB.y);
            pp[s] = fmaxf(hid, 0.0f) * wo;
        }
        const float t0 = pp[0] + __shfl_xor(pp[0], 1);
        const float t1 = pp[1] + __shfl_xor(pp[1], 1);
        float z = (lane & 1) ? t1 : t0;
        #pragma unroll
        for (int off = 2; off < 64; off <<= 1) z += __shfl_xor(z, off);
        if (lane < 2) red[wid][jp * 2 + lane] = z;
    }
    __syncthreads();
    if (t < 16) out[bi * 32 + jh * 16 + t] = red[0][t] + red[1][t] + red[2][t] + red[3][t] + rbias;
}

extern "C" void kernel_launch(void* const* d_in, const int* in_sizes, int n_in,
                              void* d_out, int out_size, void* d_ws, size_t ws_size,
                              hipStream_t stream) {
    const float* points = (const float*)d_in[0];
    const float* mw1 = (const float*)d_in[1];
    const float* mb1 = (const float*)d_in[2];
    const float* mw2 = (const float*)d_in[3];
    const float* mb2 = (const float*)d_in[4];
    const float* cw1 = (const float*)d_in[5];
    const float* cb1 = (const float*)d_in[6];
    const float* cw2 = (const float*)d_in[7];
    const float* cb2 = (const float*)d_in[8];
    const float* rw1 = (const float*)d_in[9];
    const float* rb1 = (const float*)d_in[10];
    const float* rw2 = (const float*)d_in[11];
    const float* rb2 = (const float*)d_in[12];
    float* out = (float*)d_out;

    char* ws = (char*)d_ws;
    float* metric = (float*)(ws);                  // 32*1024 f32 = 128 KB @ 0
    v8f*   cpkT   = (v8f*)(ws + 131072);           // 32*64*32 B = 64 KB
    v8f*   cpkX   = (v8f*)(ws + 196608);           // 64 KB
    float* rbase  = (float*)(ws + 262144);         // 32 KB
    float* cc     = (float*)(ws + 294912);         // 1 f32 (+pad)
    float* gamma  = (float*)(ws + 295168);         // 4 MB

    setup_kernel<<<256, 256, 0, stream>>>(points, mw1, mb1, mw2, mb2,
                                          cw1, cb1, cw2, cb2, rw1, rb1,
                                          metric, cpkT, cpkX, rbase, cc);
    christoffel_kernel<<<2048, 256, 0, stream>>>(metric, cpkT, cpkX, cc, gamma);
    ricci_kernel<<<2048, 256, 0, stream>>>(metric, rbase, rw1, rw2, rb2, gamma, out);
}

// Round 11
// 54.393 us; speedup vs baseline: 1.1212x; 1.0166x over previous
//
#include <hip/hip_runtime.h>

#define D 32
#define H 128
#define TN 256            // tanh table entries
#define TRANGE 6.0f       // table covers [-6, 6]

typedef float v2f __attribute__((ext_vector_type(2)));
typedef float v8f __attribute__((ext_vector_type(8)));

// ---------------- Stage A: metric + folded per-batch constants ----------------
// grid = 256: blk = (b, q); q = m-chunk of 128 metric outputs.
// cpkT[b][hp] (even h=2hp, table path, u-space):  {S*cbase+128, S*a1, S*a2, S*a3, cw2, 0,0,0}
// cpkX[b][hp] (odd h=2hp+1, trans path, Kc-space):{Kc*cbase,  Kc*a1, Kc*a2, Kc*a3, -2*cw2, 0,0,0}
// cc = cb2 + sum_{odd h} cw2[h]
__global__ __launch_bounds__(256) void setup_kernel(
    const float* __restrict__ points,
    const float* __restrict__ mw1, const float* __restrict__ mb1,
    const float* __restrict__ mw2, const float* __restrict__ mb2,
    const float* __restrict__ cw1, const float* __restrict__ cb1,
    const float* __restrict__ cw2, const float* __restrict__ cb2,
    const float* __restrict__ rw1, const float* __restrict__ rb1,
    float* __restrict__ metric, v8f* __restrict__ cpkT, v8f* __restrict__ cpkX,
    float* __restrict__ rbase, float* __restrict__ cc)
{
    __shared__ float p[D];
    __shared__ float h1[H];
    const int blk = blockIdx.x;
    const int b   = blk >> 3;
    const int q   = blk & 7;
    const int t   = threadIdx.x;
    if (t < D) p[t] = points[b * D + t];
    __syncthreads();

    if (t < H) {
        float acc = mb1[t];
        #pragma unroll
        for (int d = 0; d < D; ++d) acc = fmaf(p[d], mw1[d * H + t], acc);
        h1[t] = fmaxf(acc, 0.0f);
    }

    if (q == 0 && t < H) {
        constexpr float S  = (float)TN / (2.0f * TRANGE);   // 21.3333
        constexpr float Kc = 2.8853900817779268f;           // 2*log2(e)
        const int h = t;
        float cacc = cb1[h];
        #pragma unroll
        for (int d = 0; d < D; ++d) cacc = fmaf(p[d], cw1[d * H + h], cacc);
        const float a1 = cw1[32 * H + h];
        const float a2 = cw1[33 * H + h];
        const float a3 = cw1[34 * H + h];
        const float w  = cw2[h];
        v8f c;
        if ((h & 1) == 0) {         // table path
            c[0] = S * cacc + (float)(TN / 2);
            c[1] = S * a1; c[2] = S * a2; c[3] = S * a3;
            c[4] = w; c[5] = 0.0f; c[6] = 0.0f; c[7] = 0.0f;
            cpkT[b * 64 + (h >> 1)] = c;
        } else {                    // trans path
            c[0] = Kc * cacc;
            c[1] = Kc * a1; c[2] = Kc * a2; c[3] = Kc * a3;
            c[4] = -2.0f * w; c[5] = 0.0f; c[6] = 0.0f; c[7] = 0.0f;
            cpkX[b * 64 + (h >> 1)] = c;
        }
    }
    if (q == 1) {
        float racc = rb1[t];
        #pragma unroll
        for (int d = 0; d < D; ++d) racc = fmaf(p[d], rw1[d * 256 + t], racc);
        rbase[b * 256 + t] = racc;
    }
    if (q == 2 && b == 0 && t < 64) {
        float v = cw2[2 * t + 1];   // odd-h weights
        #pragma unroll
        for (int off = 32; off > 0; off >>= 1) v += __shfl_xor(v, off);
        if (t == 0) cc[0] = v + cb2[0];
    }
    __syncthreads();

    if (t < 128) {
        const int m = q * 128 + t;
        float acc = mb2[m];
        #pragma unroll 8
        for (int h = 0; h < H; ++h) acc = fmaf(h1[h], mw2[h * 1024 + m], acc);
        metric[b * 1024 + m] = acc;
    }
}

// ---------------- Stage B: fused christoffel + ricci ----------------
// Block = (b, i, jh): christoffel phase computes its 512 Gamma values (rows
// j in [jh*16, jh*16+16), all k) into 2 KB LDS — h-loop identical to R10's
// pipe-split (even h: 256-entry table; odd h: exp2+rcp). One barrier, then
// the ricci phase reduces exactly those 16 outputs (R7 structure, Gs from
// LDS broadcast reads). Ricci weights loaded only AFTER the barrier so
// register lifetimes don't overlap (R2's VGPR mistake). Gamma never touches
// global memory. grid = 2048, block = 256.
__global__ __launch_bounds__(256) void fused_kernel(
    const float* __restrict__ metric,
    const v8f* __restrict__ cpkT, const v8f* __restrict__ cpkX,
    const float* __restrict__ cc,
    const float* __restrict__ rbase,
    const float* __restrict__ rw1, const float* __restrict__ rw2,
    const float* __restrict__ rb2,
    float* __restrict__ out)
{
    __shared__ float2 tab[TN];          // 2 KB
    __shared__ float Gs[512];           // 2 KB: Gamma[j-jh*16][k]
    __shared__ float red[4][16];
    const int blk = blockIdx.x;
    const int b   = blk >> 6;
    const int i   = (blk >> 1) & 31;
    const int jh  = blk & 1;
    const int t   = threadIdx.x;

    // one-time table fill: 1 entry per thread
    constexpr float hstep = 2.0f * TRANGE / (float)TN;
    constexpr float Kc = 2.8853900817779268f;   // 2*log2(e)
    if (t < TN) {
        const float x0 = -TRANGE + t * hstep;
        const float e0 = __builtin_amdgcn_exp2f(Kc * x0);
        const float v0 = 1.0f - 2.0f * __builtin_amdgcn_rcpf(e0 + 1.0f);
        const float e1 = __builtin_amdgcn_exp2f(Kc * (x0 + hstep));
        const float v1 = 1.0f - 2.0f * __builtin_amdgcn_rcpf(e1 + 1.0f);
        tab[t] = make_float2(v0, v1 - v0);
    }

    const int j  = jh * 16 + (t >> 4);
    const int k0 = (t & 15) * 2;
    const float* __restrict__ Mb = metric + b * 1024;
    const float gij  = Mb[i * 32 + j];
    const float gjk0 = Mb[j * 32 + k0];
    const float gjk1 = Mb[j * 32 + k0 + 1];
    const float gki0 = Mb[k0 * 32 + i];
    const float gki1 = Mb[(k0 + 1) * 32 + i];
    __syncthreads();

    float acc0 = 0.0f, acc1 = 0.0f;
    const v8f* __restrict__ cpT = cpkT + b * 64;    // wave-uniform streams
    const v8f* __restrict__ cpX = cpkX + b * 64;

    #pragma unroll 4
    for (int hp = 0; hp < 64; ++hp) {
        const v8f ct = cpT[hp];
        const v8f cx = cpX[hp];
        // table path (even h)
        {
            const float pre = fmaf(gij, ct[1], ct[0]);
            float u0 = fmaf(gki0, ct[3], fmaf(gjk0, ct[2], pre));
            float u1 = fmaf(gki1, ct[3], fmaf(gjk1, ct[2], pre));
            u0 = __builtin_amdgcn_fmed3f(u0, 0.0f, (float)(TN - 1));
            u1 = __builtin_amdgcn_fmed3f(u1, 0.0f, (float)(TN - 1));
            const int   i0 = (int)u0;
            const int   i1 = (int)u1;
            const float fr0 = u0 - (float)i0;
            const float fr1 = u1 - (float)i1;
            const float2 p0 = tab[i0];  // ds_read_b64 gather
            const float2 p1 = tab[i1];
            acc0 = fmaf(fmaf(fr0, p0.y, p0.x), ct[4], acc0);
            acc1 = fmaf(fmaf(fr1, p1.y, p1.x), ct[4], acc1);
        }
        // trans path (odd h): acc += -2w * rcp(exp2(x)+1)   (+w folded into cc)
        {
            const float pre = fmaf(gij, cx[1], cx[0]);
            const float x0 = fmaf(gki0, cx[3], fmaf(gjk0, cx[2], pre));
            const float x1 = fmaf(gki1, cx[3], fmaf(gjk1, cx[2], pre));
            const float r0 = __builtin_amdgcn_rcpf(__builtin_amdgcn_exp2f(x0) + 1.0f);
            const float r1 = __builtin_amdgcn_rcpf(__builtin_amdgcn_exp2f(x1) + 1.0f);
            acc0 = fmaf(r0, cx[4], acc0);
            acc1 = fmaf(r1, cx[4], acc1);
        }
    }

    // Gamma half-tile -> LDS. Gs[(j-jh*16)*32 + k] ; (t>>4)*32 + (t&15)*2 == 2t.
    const float bias = cc[0];
    v2f res; res.x = acc0 + bias; res.y = acc1 + bias;
    *((v2f*)(Gs + 2 * t)) = res;
    __syncthreads();

    // ---- Ricci phase (R7 structure; Gs from LDS, weights loaded NOW) ----
    float w[33];
    #pragma unroll
    for (int f = 0; f < 33; ++f) w[f] = rw1[(32 + f) * 256 + t];
    const float rbv   = rbase[b * 256 + t];
    const float wo    = rw2[t];
    const float rbias = rb2[0];
    const float* __restrict__ Mrow = Mb + i * 32 + jh * 16;

    const int wid  = t >> 6;
    const int lane = t & 63;

    #pragma unroll 2
    for (int jp = 0; jp < 8; ++jp) {
        float pp[2];
        #pragma unroll
        for (int s = 0; s < 2; ++s) {
            const int jj = jp * 2 + s;
            v2f hA = (v2f)(0.0f), hB = (v2f)(0.0f);
            #pragma unroll
            for (int k4 = 0; k4 < 8; ++k4) {
                const float4 g = ((const float4*)Gs)[jj * 8 + k4];  // LDS broadcast
                v2f glo; glo.x = g.x; glo.y = g.y;
                v2f ghi; ghi.x = g.z; ghi.y = g.w;
                v2f wlo; wlo.x = w[k4 * 4 + 1]; wlo.y = w[k4 * 4 + 2];
                v2f whi; whi.x = w[k4 * 4 + 3]; whi.y = w[k4 * 4 + 4];
                hA = glo * wlo + hA;
                hB = ghi * whi + hB;
            }
            const float hid = fmaf(Mrow[jj], w[0], rbv) + (hA.x + hA.y) + (hB.x + hB.y);
            pp[s] = fmaxf(hid, 0.0f) * wo;
        }
        const float t0 = pp[0] + __shfl_xor(pp[0], 1);
        const float t1 = pp[1] + __shfl_xor(pp[1], 1);
        float z = (lane & 1) ? t1 : t0;
        #pragma unroll
        for (int off = 2; off < 64; off <<= 1) z += __shfl_xor(z, off);
        if (lane < 2) red[wid][jp * 2 + lane] = z;
    }
    __syncthreads();
    if (t < 16)
        out[((b * 32 + i) * 32) + jh * 16 + t] =
            red[0][t] + red[1][t] + red[2][t] + red[3][t] + rbias;
}

extern "C" void kernel_launch(void* const* d_in, const int* in_sizes, int n_in,
                              void* d_out, int out_size, void* d_ws, size_t ws_size,
                              hipStream_t stream) {
    const float* points = (const float*)d_in[0];
    const float* mw1 = (const float*)d_in[1];
    const float* mb1 = (const float*)d_in[2];
    const float* mw2 = (const float*)d_in[3];
    const float* mb2 = (const float*)d_in[4];
    const float* cw1 = (const float*)d_in[5];
    const float* cb1 = (const float*)d_in[6];
    const float* cw2 = (const float*)d_in[7];
    const float* cb2 = (const float*)d_in[8];
    const float* rw1 = (const float*)d_in[9];
    const float* rb1 = (const float*)d_in[10];
    const float* rw2 = (const float*)d_in[11];
    const float* rb2 = (const float*)d_in[12];
    float* out = (float*)d_out;

    char* ws = (char*)d_ws;
    float* metric = (float*)(ws);                  // 32*1024 f32 = 128 KB @ 0
    v8f*   cpkT   = (v8f*)(ws + 131072);           // 32*64*32 B = 64 KB
    v8f*   cpkX   = (v8f*)(ws + 196608);           // 64 KB
    float* rbase  = (float*)(ws + 262144);         // 32 KB
    float* cc     = (float*)(ws + 294912);         // 1 f32 (+pad)

    setup_kernel<<<256, 256, 0, stream>>>(points, mw1, mb1, mw2, mb2,
                                          cw1, cb1, cw2, cb2, rw1, rb1,
                                          metric, cpkT, cpkX, rbase, cc);
    fused_kernel<<<2048, 256, 0, stream>>>(metric, cpkT, cpkX, cc,
                                           rbase, rw1, rw2, rb2, out);
}

// Round 12
// 52.978 us; speedup vs baseline: 1.1511x; 1.0267x over previous
//
#include <hip/hip_runtime.h>

#define D 32
#define H 128
#define TN 256            // tanh table entries
#define TRANGE 6.0f       // table covers [-6, 6]

typedef float v2f __attribute__((ext_vector_type(2)));
typedef float v8f __attribute__((ext_vector_type(8)));

// ---------------- Stage A: metric + folded per-batch constants ----------------
// (identical to R11)
__global__ __launch_bounds__(256) void setup_kernel(
    const float* __restrict__ points,
    const float* __restrict__ mw1, const float* __restrict__ mb1,
    const float* __restrict__ mw2, const float* __restrict__ mb2,
    const float* __restrict__ cw1, const float* __restrict__ cb1,
    const float* __restrict__ cw2, const float* __restrict__ cb2,
    const float* __restrict__ rw1, const float* __restrict__ rb1,
    float* __restrict__ metric, v8f* __restrict__ cpkT, v8f* __restrict__ cpkX,
    float* __restrict__ rbase, float* __restrict__ cc)
{
    __shared__ float p[D];
    __shared__ float h1[H];
    const int blk = blockIdx.x;
    const int b   = blk >> 3;
    const int q   = blk & 7;
    const int t   = threadIdx.x;
    if (t < D) p[t] = points[b * D + t];
    __syncthreads();

    if (t < H) {
        float acc = mb1[t];
        #pragma unroll
        for (int d = 0; d < D; ++d) acc = fmaf(p[d], mw1[d * H + t], acc);
        h1[t] = fmaxf(acc, 0.0f);
    }

    if (q == 0 && t < H) {
        constexpr float S  = (float)TN / (2.0f * TRANGE);   // 21.3333
        constexpr float Kc = 2.8853900817779268f;           // 2*log2(e)
        const int h = t;
        float cacc = cb1[h];
        #pragma unroll
        for (int d = 0; d < D; ++d) cacc = fmaf(p[d], cw1[d * H + h], cacc);
        const float a1 = cw1[32 * H + h];
        const float a2 = cw1[33 * H + h];
        const float a3 = cw1[34 * H + h];
        const float w  = cw2[h];
        v8f c;
        if ((h & 1) == 0) {         // table path
            c[0] = S * cacc + (float)(TN / 2);
            c[1] = S * a1; c[2] = S * a2; c[3] = S * a3;
            c[4] = w; c[5] = 0.0f; c[6] = 0.0f; c[7] = 0.0f;
            cpkT[b * 64 + (h >> 1)] = c;
        } else {                    // trans path
            c[0] = Kc * cacc;
            c[1] = Kc * a1; c[2] = Kc * a2; c[3] = Kc * a3;
            c[4] = -2.0f * w; c[5] = 0.0f; c[6] = 0.0f; c[7] = 0.0f;
            cpkX[b * 64 + (h >> 1)] = c;
        }
    }
    if (q == 1) {
        float racc = rb1[t];
        #pragma unroll
        for (int d = 0; d < D; ++d) racc = fmaf(p[d], rw1[d * 256 + t], racc);
        rbase[b * 256 + t] = racc;
    }
    if (q == 2 && b == 0 && t < 64) {
        float v = cw2[2 * t + 1];   // odd-h weights
        #pragma unroll
        for (int off = 32; off > 0; off >>= 1) v += __shfl_xor(v, off);
        if (t == 0) cc[0] = v + cb2[0];
    }
    __syncthreads();

    if (t < 128) {
        const int m = q * 128 + t;
        float acc = mb2[m];
        #pragma unroll 8
        for (int h = 0; h < H; ++h) acc = fmaf(h1[h], mw2[h * 1024 + m], acc);
        metric[b * 1024 + m] = acc;
    }
}

// ---------------- Stage B: fused christoffel + ricci ----------------
// Christoffel phase identical to R11 (pipe-split h-loop -> Gs in LDS).
// Ricci phase v2: only waves 0-1 (threads 0-127) participate; each thread
// owns TWO hidden units (h=t, h=t+128), sharing each Gs float4 broadcast
// between both FMA sets and summing both contributions before the reduce.
// LDS broadcast requests scale with WAVES -> halved (4096 -> 2048 per CU).
// grid = 2048, block = 256.
__global__ __launch_bounds__(256) void fused_kernel(
    const float* __restrict__ metric,
    const v8f* __restrict__ cpkT, const v8f* __restrict__ cpkX,
    const float* __restrict__ cc,
    const float* __restrict__ rbase,
    const float* __restrict__ rw1, const float* __restrict__ rw2,
    const float* __restrict__ rb2,
    float* __restrict__ out)
{
    __shared__ float2 tab[TN];          // 2 KB
    __shared__ float Gs[512];           // 2 KB: Gamma[j-jh*16][k]
    __shared__ float red[2][16];
    const int blk = blockIdx.x;
    const int b   = blk >> 6;
    const int i   = (blk >> 1) & 31;
    const int jh  = blk & 1;
    const int t   = threadIdx.x;

    // one-time table fill: 1 entry per thread
    constexpr float hstep = 2.0f * TRANGE / (float)TN;
    constexpr float Kc = 2.8853900817779268f;   // 2*log2(e)
    if (t < TN) {
        const float x0 = -TRANGE + t * hstep;
        const float e0 = __builtin_amdgcn_exp2f(Kc * x0);
        const float v0 = 1.0f - 2.0f * __builtin_amdgcn_rcpf(e0 + 1.0f);
        const float e1 = __builtin_amdgcn_exp2f(Kc * (x0 + hstep));
        const float v1 = 1.0f - 2.0f * __builtin_amdgcn_rcpf(e1 + 1.0f);
        tab[t] = make_float2(v0, v1 - v0);
    }

    const int j  = jh * 16 + (t >> 4);
    const int k0 = (t & 15) * 2;
    const float* __restrict__ Mb = metric + b * 1024;
    const float gij  = Mb[i * 32 + j];
    const float gjk0 = Mb[j * 32 + k0];
    const float gjk1 = Mb[j * 32 + k0 + 1];
    const float gki0 = Mb[k0 * 32 + i];
    const float gki1 = Mb[(k0 + 1) * 32 + i];
    __syncthreads();

    float acc0 = 0.0f, acc1 = 0.0f;
    const v8f* __restrict__ cpT = cpkT + b * 64;    // wave-uniform streams
    const v8f* __restrict__ cpX = cpkX + b * 64;

    #pragma unroll 4
    for (int hp = 0; hp < 64; ++hp) {
        const v8f ct = cpT[hp];
        const v8f cx = cpX[hp];
        // table path (even h)
        {
            const float pre = fmaf(gij, ct[1], ct[0]);
            float u0 = fmaf(gki0, ct[3], fmaf(gjk0, ct[2], pre));
            float u1 = fmaf(gki1, ct[3], fmaf(gjk1, ct[2], pre));
            u0 = __builtin_amdgcn_fmed3f(u0, 0.0f, (float)(TN - 1));
            u1 = __builtin_amdgcn_fmed3f(u1, 0.0f, (float)(TN - 1));
            const int   i0 = (int)u0;
            const int   i1 = (int)u1;
            const float fr0 = u0 - (float)i0;
            const float fr1 = u1 - (float)i1;
            const float2 p0 = tab[i0];  // ds_read_b64 gather
            const float2 p1 = tab[i1];
            acc0 = fmaf(fmaf(fr0, p0.y, p0.x), ct[4], acc0);
            acc1 = fmaf(fmaf(fr1, p1.y, p1.x), ct[4], acc1);
        }
        // trans path (odd h): acc += -2w * rcp(exp2(x)+1)   (+w folded into cc)
        {
            const float pre = fmaf(gij, cx[1], cx[0]);
            const float x0 = fmaf(gki0, cx[3], fmaf(gjk0, cx[2], pre));
            const float x1 = fmaf(gki1, cx[3], fmaf(gjk1, cx[2], pre));
            const float r0 = __builtin_amdgcn_rcpf(__builtin_amdgcn_exp2f(x0) + 1.0f);
            const float r1 = __builtin_amdgcn_rcpf(__builtin_amdgcn_exp2f(x1) + 1.0f);
            acc0 = fmaf(r0, cx[4], acc0);
            acc1 = fmaf(r1, cx[4], acc1);
        }
    }

    // Gamma half-tile -> LDS. Gs[(j-jh*16)*32 + k]; (t>>4)*32 + (t&15)*2 == 2t.
    const float bias = cc[0];
    v2f res; res.x = acc0 + bias; res.y = acc1 + bias;
    *((v2f*)(Gs + 2 * t)) = res;

    // ---- Ricci phase: issue weight loads before the barrier (latency overlap) ----
    float wA[33], wB[33];
    float rbvA = 0.0f, rbvB = 0.0f, woA = 0.0f, woB = 0.0f;
    if (t < 128) {
        #pragma unroll
        for (int f = 0; f < 33; ++f) {
            wA[f] = rw1[(32 + f) * 256 + t];
            wB[f] = rw1[(32 + f) * 256 + t + 128];
        }
        rbvA = rbase[b * 256 + t];
        rbvB = rbase[b * 256 + t + 128];
        woA  = rw2[t];
        woB  = rw2[t + 128];
    }
    __syncthreads();

    const float rbias = rb2[0];
    const float* __restrict__ Mrow = Mb + i * 32 + jh * 16;

    if (t < 128) {
        const int wid  = t >> 6;        // 0 or 1
        const int lane = t & 63;

        #pragma unroll 2
        for (int jp = 0; jp < 8; ++jp) {
            float pp[2];
            #pragma unroll
            for (int s = 0; s < 2; ++s) {
                const int jj = jp * 2 + s;
                float hidA = fmaf(Mrow[jj], wA[0], rbvA);
                float hidB = fmaf(Mrow[jj], wB[0], rbvB);
                #pragma unroll
                for (int k4 = 0; k4 < 8; ++k4) {
                    const float4 g = ((const float4*)Gs)[jj * 8 + k4];  // LDS broadcast
                    hidA = fmaf(g.x, wA[k4 * 4 + 1], hidA);
                    hidA = fmaf(g.y, wA[k4 * 4 + 2], hidA);
                    hidA = fmaf(g.z, wA[k4 * 4 + 3], hidA);
                    hidA = fmaf(g.w, wA[k4 * 4 + 4], hidA);
                    hidB = fmaf(g.x, wB[k4 * 4 + 1], hidB);
                    hidB = fmaf(g.y, wB[k4 * 4 + 2], hidB);
                    hidB = fmaf(g.z, wB[k4 * 4 + 3], hidB);
                    hidB = fmaf(g.w, wB[k4 * 4 + 4], hidB);
                }
                pp[s] = fmaxf(hidA, 0.0f) * woA + fmaxf(hidB, 0.0f) * woB;
            }
            const float t0 = pp[0] + __shfl_xor(pp[0], 1);
            const float t1 = pp[1] + __shfl_xor(pp[1], 1);
            float z = (lane & 1) ? t1 : t0;
            #pragma unroll
            for (int off = 2; off < 64; off <<= 1) z += __shfl_xor(z, off);
            if (lane < 2) red[wid][jp * 2 + lane] = z;
        }
    }
    __syncthreads();
    if (t < 16)
        out[((b * 32 + i) * 32) + jh * 16 + t] = red[0][t] + red[1][t] + rbias;
}

extern "C" void kernel_launch(void* const* d_in, const int* in_sizes, int n_in,
                              void* d_out, int out_size, void* d_ws, size_t ws_size,
                              hipStream_t stream) {
    const float* points = (const float*)d_in[0];
    const float* mw1 = (const float*)d_in[1];
    const float* mb1 = (const float*)d_in[2];
    const float* mw2 = (const float*)d_in[3];
    const float* mb2 = (const float*)d_in[4];
    const float* cw1 = (const float*)d_in[5];
    const float* cb1 = (const float*)d_in[6];
    const float* cw2 = (const float*)d_in[7];
    const float* cb2 = (const float*)d_in[8];
    const float* rw1 = (const float*)d_in[9];
    const float* rb1 = (const float*)d_in[10];
    const float* rw2 = (const float*)d_in[11];
    const float* rb2 = (const float*)d_in[12];
    float* out = (float*)d_out;

    char* ws = (char*)d_ws;
    float* metric = (float*)(ws);                  // 32*1024 f32 = 128 KB @ 0
    v8f*   cpkT   = (v8f*)(ws + 131072);           // 32*64*32 B = 64 KB
    v8f*   cpkX   = (v8f*)(ws + 196608);           // 64 KB
    float* rbase  = (float*)(ws + 262144);         // 32 KB
    float* cc     = (float*)(ws + 294912);         // 1 f32 (+pad)

    setup_kernel<<<256, 256, 0, stream>>>(points, mw1, mb1, mw2, mb2,
                                          cw1, cb1, cw2, cb2, rw1, rb1,
                                          metric, cpkT, cpkX, rbase, cc);
    fused_kernel<<<2048, 256, 0, stream>>>(metric, cpkT, cpkX, cc,
                                           rbase, rw1, rw2, rb2, out);
}

// Round 13
// 50.975 us; speedup vs baseline: 1.1963x; 1.0393x over previous
//
#include <hip/hip_runtime.h>

#define D 32
#define H 128
#define TN 4096           // nearest-neighbor tanh table entries
#define TRANGE 6.0f       // table covers [-6, 6]

typedef float v2f __attribute__((ext_vector_type(2)));
typedef float v8f __attribute__((ext_vector_type(8)));

// ---------------- Stage A: metric + folded per-batch constants ----------------
// cpkT[b][hp] (even h=2hp, nearest-table path, index-space incl. +0.5 rounding):
//   {S*cbase + TN/2 + 0.5, S*a1, S*a2, S*a3, cw2, 0,0,0}
// cpkX[b][hp] (odd h=2hp+1, trans path, Kc-space):
//   {Kc*cbase, Kc*a1, Kc*a2, Kc*a3, -2*cw2, 0,0,0}
// cc = cb2 + sum_{odd h} cw2[h]
__global__ __launch_bounds__(256) void setup_kernel(
    const float* __restrict__ points,
    const float* __restrict__ mw1, const float* __restrict__ mb1,
    const float* __restrict__ mw2, const float* __restrict__ mb2,
    const float* __restrict__ cw1, const float* __restrict__ cb1,
    const float* __restrict__ cw2, const float* __restrict__ cb2,
    const float* __restrict__ rw1, const float* __restrict__ rb1,
    float* __restrict__ metric, v8f* __restrict__ cpkT, v8f* __restrict__ cpkX,
    float* __restrict__ rbase, float* __restrict__ cc)
{
    __shared__ float p[D];
    __shared__ float h1[H];
    const int blk = blockIdx.x;
    const int b   = blk >> 3;
    const int q   = blk & 7;
    const int t   = threadIdx.x;
    if (t < D) p[t] = points[b * D + t];
    __syncthreads();

    if (t < H) {
        float acc = mb1[t];
        #pragma unroll
        for (int d = 0; d < D; ++d) acc = fmaf(p[d], mw1[d * H + t], acc);
        h1[t] = fmaxf(acc, 0.0f);
    }

    if (q == 0 && t < H) {
        constexpr float S  = (float)TN / (2.0f * TRANGE);   // 341.333
        constexpr float Kc = 2.8853900817779268f;           // 2*log2(e)
        const int h = t;
        float cacc = cb1[h];
        #pragma unroll
        for (int d = 0; d < D; ++d) cacc = fmaf(p[d], cw1[d * H + h], cacc);
        const float a1 = cw1[32 * H + h];
        const float a2 = cw1[33 * H + h];
        const float a3 = cw1[34 * H + h];
        const float w  = cw2[h];
        v8f c;
        if ((h & 1) == 0) {         // nearest-table path
            c[0] = S * cacc + (float)(TN / 2) + 0.5f;
            c[1] = S * a1; c[2] = S * a2; c[3] = S * a3;
            c[4] = w; c[5] = 0.0f; c[6] = 0.0f; c[7] = 0.0f;
            cpkT[b * 64 + (h >> 1)] = c;
        } else {                    // trans path
            c[0] = Kc * cacc;
            c[1] = Kc * a1; c[2] = Kc * a2; c[3] = Kc * a3;
            c[4] = -2.0f * w; c[5] = 0.0f; c[6] = 0.0f; c[7] = 0.0f;
            cpkX[b * 64 + (h >> 1)] = c;
        }
    }
    if (q == 1) {
        float racc = rb1[t];
        #pragma unroll
        for (int d = 0; d < D; ++d) racc = fmaf(p[d], rw1[d * 256 + t], racc);
        rbase[b * 256 + t] = racc;
    }
    if (q == 2 && b == 0 && t < 64) {
        float v = cw2[2 * t + 1];   // odd-h weights
        #pragma unroll
        for (int off = 32; off > 0; off >>= 1) v += __shfl_xor(v, off);
        if (t == 0) cc[0] = v + cb2[0];
    }
    __syncthreads();

    if (t < 128) {
        const int m = q * 128 + t;
        float acc = mb2[m];
        #pragma unroll 8
        for (int h = 0; h < H; ++h) acc = fmaf(h1[h], mw2[h * 1024 + m], acc);
        metric[b * 1024 + m] = acc;
    }
}

// ---------------- Stage B: fused christoffel + ricci ----------------
// Christoffel h-loop, instruction-dieted:
//   even h: nearest-neighbor 4096-entry table — 2 pk_fma (u) + 2 med3 +
//           2 cvt + 2 ds_read_b32 + 1 pk_fma (acc); no interp math.
//   odd h : packed trans — 2 pk_fma (x) + 2 exp2 + 1 pk_add + 2 rcp + 1 pk_fma.
// Ricci phase: 2 waves, 2 h-units/thread, v2f-packed FMA chain.
// grid = 2048 (b,i,jh), block = 256.
__global__ __launch_bounds__(256) void fused_kernel(
    const float* __restrict__ metric,
    const v8f* __restrict__ cpkT, const v8f* __restrict__ cpkX,
    const float* __restrict__ cc,
    const float* __restrict__ rbase,
    const float* __restrict__ rw1, const float* __restrict__ rw2,
    const float* __restrict__ rb2,
    float* __restrict__ out)
{
    __shared__ float tab[TN];           // 16 KB: tanh values, nearest lookup
    __shared__ float Gs[512];           // 2 KB: Gamma[j-jh*16][k]
    __shared__ float red[2][16];
    const int blk = blockIdx.x;
    const int b   = blk >> 6;
    const int i   = (blk >> 1) & 31;
    const int jh  = blk & 1;
    const int t   = threadIdx.x;

    // one-time table fill: 16 entries per thread
    constexpr float hstep = 2.0f * TRANGE / (float)TN;
    constexpr float Kc = 2.8853900817779268f;   // 2*log2(e)
    #pragma unroll
    for (int e = 0; e < TN / 256; ++e) {
        const int idx = e * 256 + t;
        const float x = -TRANGE + idx * hstep;
        const float ex = __builtin_amdgcn_exp2f(Kc * x);
        tab[idx] = 1.0f - 2.0f * __builtin_amdgcn_rcpf(ex + 1.0f);
    }

    const int j  = jh * 16 + (t >> 4);
    const int k0 = (t & 15) * 2;
    const float* __restrict__ Mb = metric + b * 1024;
    const float gij  = Mb[i * 32 + j];
    v2f gjk2; gjk2.x = Mb[j * 32 + k0];       gjk2.y = Mb[j * 32 + k0 + 1];
    v2f gki2; gki2.x = Mb[k0 * 32 + i];       gki2.y = Mb[(k0 + 1) * 32 + i];
    __syncthreads();

    v2f acc = (v2f)(0.0f);
    const v8f* __restrict__ cpT = cpkT + b * 64;    // wave-uniform streams
    const v8f* __restrict__ cpX = cpkX + b * 64;

    #pragma unroll 4
    for (int hp = 0; hp < 64; ++hp) {
        const v8f ct = cpT[hp];
        const v8f cx = cpX[hp];
        // nearest-table path (even h)
        {
            const float pre = fmaf(gij, ct[1], ct[0]);
            v2f u = gjk2 * ct[2] + (v2f)(pre);          // pk_fma
            u = gki2 * ct[3] + u;                       // pk_fma
            const float u0 = __builtin_amdgcn_fmed3f(u.x, 0.0f, (float)(TN - 1));
            const float u1 = __builtin_amdgcn_fmed3f(u.y, 0.0f, (float)(TN - 1));
            v2f v;
            v.x = tab[(int)u0];                         // ds_read_b32 gather
            v.y = tab[(int)u1];
            acc = v * ct[4] + acc;                      // pk_fma
        }
        // trans path (odd h): acc += -2w * rcp(exp2(x)+1)   (+w folded into cc)
        {
            const float pre = fmaf(gij, cx[1], cx[0]);
            v2f x = gjk2 * cx[2] + (v2f)(pre);          // pk_fma
            x = gki2 * cx[3] + x;                       // pk_fma
            v2f e;
            e.x = __builtin_amdgcn_exp2f(x.x);
            e.y = __builtin_amdgcn_exp2f(x.y);
            e = e + (v2f)(1.0f);                        // pk_add
            v2f r;
            r.x = __builtin_amdgcn_rcpf(e.x);
            r.y = __builtin_amdgcn_rcpf(e.y);
            acc = r * cx[4] + acc;                      // pk_fma
        }
    }

    // Gamma half-tile -> LDS. Gs[(j-jh*16)*32 + k]; (t>>4)*32 + (t&15)*2 == 2t.
    const float bias = cc[0];
    v2f res = acc + (v2f)(bias);
    *((v2f*)(Gs + 2 * t)) = res;

    // ---- Ricci phase: 2 waves, 2 h-units/thread, packed FMA ----
    float wA[33], wB[33];
    float rbvA = 0.0f, rbvB = 0.0f, woA = 0.0f, woB = 0.0f;
    if (t < 128) {
        #pragma unroll
        for (int f = 0; f < 33; ++f) {
            wA[f] = rw1[(32 + f) * 256 + t];
            wB[f] = rw1[(32 + f) * 256 + t + 128];
        }
        rbvA = rbase[b * 256 + t];
        rbvB = rbase[b * 256 + t + 128];
        woA  = rw2[t];
        woB  = rw2[t + 128];
    }
    __syncthreads();

    const float rbias = rb2[0];
    const float* __restrict__ Mrow = Mb + i * 32 + jh * 16;

    if (t < 128) {
        const int wid  = t >> 6;        // 0 or 1
        const int lane = t & 63;

        #pragma unroll 2
        for (int jp = 0; jp < 8; ++jp) {
            float pp[2];
            #pragma unroll
            for (int s = 0; s < 2; ++s) {
                const int jj = jp * 2 + s;
                const float m0 = Mrow[jj];
                v2f hAv = (v2f)(0.0f), hBv = (v2f)(0.0f);
                #pragma unroll
                for (int k4 = 0; k4 < 8; ++k4) {
                    const float4 g = ((const float4*)Gs)[jj * 8 + k4];  // LDS broadcast
                    v2f glo; glo.x = g.x; glo.y = g.y;
                    v2f ghi; ghi.x = g.z; ghi.y = g.w;
                    v2f wloA; wloA.x = wA[k4 * 4 + 1]; wloA.y = wA[k4 * 4 + 2];
                    v2f whiA; whiA.x = wA[k4 * 4 + 3]; whiA.y = wA[k4 * 4 + 4];
                    v2f wloB; wloB.x = wB[k4 * 4 + 1]; wloB.y = wB[k4 * 4 + 2];
                    v2f whiB; whiB.x = wB[k4 * 4 + 3]; whiB.y = wB[k4 * 4 + 4];
                    hAv = glo * wloA + hAv;             // pk_fma
                    hAv = ghi * whiA + hAv;
                    hBv = glo * wloB + hBv;
                    hBv = ghi * whiB + hBv;
                }
                const float hidA = fmaf(m0, wA[0], rbvA) + (hAv.x + hAv.y);
                const float hidB = fmaf(m0, wB[0], rbvB) + (hBv.x + hBv.y);
                pp[s] = fmaxf(hidA, 0.0f) * woA + fmaxf(hidB, 0.0f) * woB;
            }
            const float t0 = pp[0] + __shfl_xor(pp[0], 1);
            const float t1 = pp[1] + __shfl_xor(pp[1], 1);
            float z = (lane & 1) ? t1 : t0;
            #pragma unroll
            for (int off = 2; off < 64; off <<= 1) z += __shfl_xor(z, off);
            if (lane < 2) red[wid][jp * 2 + lane] = z;
        }
    }
    __syncthreads();
    if (t < 16)
        out[((b * 32 + i) * 32) + jh * 16 + t] = red[0][t] + red[1][t] + rbias;
}

extern "C" void kernel_launch(void* const* d_in, const int* in_sizes, int n_in,
                              void* d_out, int out_size, void* d_ws, size_t ws_size,
                              hipStream_t stream) {
    const float* points = (const float*)d_in[0];
    const float* mw1 = (const float*)d_in[1];
    const float* mb1 = (const float*)d_in[2];
    const float* mw2 = (const float*)d_in[3];
    const float* mb2 = (const float*)d_in[4];
    const float* cw1 = (const float*)d_in[5];
    const float* cb1 = (const float*)d_in[6];
    const float* cw2 = (const float*)d_in[7];
    const float* cb2 = (const float*)d_in[8];
    const float* rw1 = (const float*)d_in[9];
    const float* rb1 = (const float*)d_in[10];
    const float* rw2 = (const float*)d_in[11];
    const float* rb2 = (const float*)d_in[12];
    float* out = (float*)d_out;

    char* ws = (char*)d_ws;
    float* metric = (float*)(ws);                  // 32*1024 f32 = 128 KB @ 0
    v8f*   cpkT   = (v8f*)(ws + 131072);           // 32*64*32 B = 64 KB
    v8f*   cpkX   = (v8f*)(ws + 196608);           // 64 KB
    float* rbase  = (float*)(ws + 262144);         // 32 KB
    float* cc     = (float*)(ws + 294912);         // 1 f32 (+pad)

    setup_kernel<<<256, 256, 0, stream>>>(points, mw1, mb1, mw2, mb2,
                                          cw1, cb1, cw2, cb2, rw1, rb1,
                                          metric, cpkT, cpkX, rbase, cc);
    fused_kernel<<<2048, 256, 0, stream>>>(metric, cpkT, cpkX, cc,
                                           rbase, rw1, rw2, rb2, out);
}

// Round 14
// 49.820 us; speedup vs baseline: 1.2241x; 1.0232x over previous
//
#include <hip/hip_runtime.h>

#define D 32
#define H 128
#define TN 4096           // nearest-neighbor tanh table entries
#define TRANGE 6.0f       // table covers [-6, 6]

typedef float v2f __attribute__((ext_vector_type(2)));
typedef float v8f __attribute__((ext_vector_type(8)));

// ---------------- Stage A: metric + folded per-batch constants ----------------
// 3:1 split: h with (h&3)!=3 -> nearest-table path (cpkT, 96/b);
//            h with (h&3)==3 -> trans path (cpkX, 32/b).
// cpkT entry: {S*cbase + TN/2 + 0.5, S*a1, S*a2, S*a3, cw2, 0,0,0}
// cpkX entry: {Kc*cbase, Kc*a1, Kc*a2, Kc*a3, -2*cw2, 0,0,0}
// cc = cb2 + sum_{trans h} cw2[h]
__global__ __launch_bounds__(256) void setup_kernel(
    const float* __restrict__ points,
    const float* __restrict__ mw1, const float* __restrict__ mb1,
    const float* __restrict__ mw2, const float* __restrict__ mb2,
    const float* __restrict__ cw1, const float* __restrict__ cb1,
    const float* __restrict__ cw2, const float* __restrict__ cb2,
    const float* __restrict__ rw1, const float* __restrict__ rb1,
    float* __restrict__ metric, v8f* __restrict__ cpkT, v8f* __restrict__ cpkX,
    float* __restrict__ rbase, float* __restrict__ cc)
{
    __shared__ float p[D];
    __shared__ float h1[H];
    const int blk = blockIdx.x;
    const int b   = blk >> 3;
    const int q   = blk & 7;
    const int t   = threadIdx.x;
    if (t < D) p[t] = points[b * D + t];
    __syncthreads();

    if (t < H) {
        float acc = mb1[t];
        #pragma unroll
        for (int d = 0; d < D; ++d) acc = fmaf(p[d], mw1[d * H + t], acc);
        h1[t] = fmaxf(acc, 0.0f);
    }

    if (q == 0 && t < H) {
        constexpr float S  = (float)TN / (2.0f * TRANGE);   // 341.333
        constexpr float Kc = 2.8853900817779268f;           // 2*log2(e)
        const int h = t;
        float cacc = cb1[h];
        #pragma unroll
        for (int d = 0; d < D; ++d) cacc = fmaf(p[d], cw1[d * H + h], cacc);
        const float a1 = cw1[32 * H + h];
        const float a2 = cw1[33 * H + h];
        const float a3 = cw1[34 * H + h];
        const float w  = cw2[h];
        v8f c;
        if ((h & 3) != 3) {         // nearest-table path (3 of 4)
            c[0] = S * cacc + (float)(TN / 2) + 0.5f;
            c[1] = S * a1; c[2] = S * a2; c[3] = S * a3;
            c[4] = w; c[5] = 0.0f; c[6] = 0.0f; c[7] = 0.0f;
            cpkT[b * 96 + (h >> 2) * 3 + (h & 3)] = c;
        } else {                    // trans path (1 of 4)
            c[0] = Kc * cacc;
            c[1] = Kc * a1; c[2] = Kc * a2; c[3] = Kc * a3;
            c[4] = -2.0f * w; c[5] = 0.0f; c[6] = 0.0f; c[7] = 0.0f;
            cpkX[b * 32 + (h >> 2)] = c;
        }
    }
    if (q == 1) {
        float racc = rb1[t];
        #pragma unroll
        for (int d = 0; d < D; ++d) racc = fmaf(p[d], rw1[d * 256 + t], racc);
        rbase[b * 256 + t] = racc;
    }
    if (q == 2 && b == 0 && t < 32) {
        float v = cw2[4 * t + 3];   // trans-h weights
        #pragma unroll
        for (int off = 16; off > 0; off >>= 1) v += __shfl_xor(v, off);
        if (t == 0) cc[0] = v + cb2[0];
    }
    __syncthreads();

    if (t < 128) {
        const int m = q * 128 + t;
        float acc = mb2[m];
        #pragma unroll 8
        for (int h = 0; h < H; ++h) acc = fmaf(h1[h], mw2[h * 1024 + m], acc);
        metric[b * 1024 + m] = acc;
    }
}

// ---------------- Stage B: fused christoffel + ricci ----------------
// 3:1 rebalanced h-loop (32 groups of 4h): 3 nearest-table h's (8 VALU insts
// + 2 ds_read_b32 each) + 1 trans h (5 VALU + 4 trans). SIMD-issue and
// per-CU LDS pipes both ~25-29k cyc — balanced.
// Ricci phase: 2 waves, 2 h-units/thread, v2f-packed FMA chain.
// grid = 2048 (b,i,jh), block = 256.
__global__ __launch_bounds__(256) void fused_kernel(
    const float* __restrict__ metric,
    const v8f* __restrict__ cpkT, const v8f* __restrict__ cpkX,
    const float* __restrict__ cc,
    const float* __restrict__ rbase,
    const float* __restrict__ rw1, const float* __restrict__ rw2,
    const float* __restrict__ rb2,
    float* __restrict__ out)
{
    __shared__ float tab[TN];           // 16 KB: tanh values, nearest lookup
    __shared__ float Gs[512];           // 2 KB: Gamma[j-jh*16][k]
    __shared__ float red[2][16];
    const int blk = blockIdx.x;
    const int b   = blk >> 6;
    const int i   = (blk >> 1) & 31;
    const int jh  = blk & 1;
    const int t   = threadIdx.x;

    // one-time table fill: 16 entries per thread
    constexpr float hstep = 2.0f * TRANGE / (float)TN;
    constexpr float Kc = 2.8853900817779268f;   // 2*log2(e)
    #pragma unroll
    for (int e = 0; e < TN / 256; ++e) {
        const int idx = e * 256 + t;
        const float x = -TRANGE + idx * hstep;
        const float ex = __builtin_amdgcn_exp2f(Kc * x);
        tab[idx] = 1.0f - 2.0f * __builtin_amdgcn_rcpf(ex + 1.0f);
    }

    const int j  = jh * 16 + (t >> 4);
    const int k0 = (t & 15) * 2;
    const float* __restrict__ Mb = metric + b * 1024;
    const float gij  = Mb[i * 32 + j];
    v2f gjk2; gjk2.x = Mb[j * 32 + k0];       gjk2.y = Mb[j * 32 + k0 + 1];
    v2f gki2; gki2.x = Mb[k0 * 32 + i];       gki2.y = Mb[(k0 + 1) * 32 + i];
    __syncthreads();

    v2f acc = (v2f)(0.0f);
    const v8f* __restrict__ cpT = cpkT + b * 96;    // wave-uniform streams
    const v8f* __restrict__ cpX = cpkX + b * 32;

    #pragma unroll 2
    for (int hp = 0; hp < 32; ++hp) {
        const v8f c0 = cpT[hp * 3 + 0];
        const v8f c1 = cpT[hp * 3 + 1];
        const v8f c2 = cpT[hp * 3 + 2];
        const v8f cx = cpX[hp];
        // three nearest-table h's
        #pragma unroll
        for (int s = 0; s < 3; ++s) {
            const v8f c = (s == 0) ? c0 : ((s == 1) ? c1 : c2);
            const float pre = fmaf(gij, c[1], c[0]);
            v2f u = gjk2 * c[2] + (v2f)(pre);           // pk_fma
            u = gki2 * c[3] + u;                        // pk_fma
            const float u0 = __builtin_amdgcn_fmed3f(u.x, 0.0f, (float)(TN - 1));
            const float u1 = __builtin_amdgcn_fmed3f(u.y, 0.0f, (float)(TN - 1));
            v2f v;
            v.x = tab[(int)u0];                         // ds_read_b32 gather
            v.y = tab[(int)u1];
            acc = v * c[4] + acc;                       // pk_fma
        }
        // one trans h: acc += -2w * rcp(exp2(x)+1)   (+w folded into cc)
        {
            const float pre = fmaf(gij, cx[1], cx[0]);
            v2f x = gjk2 * cx[2] + (v2f)(pre);          // pk_fma
            x = gki2 * cx[3] + x;                       // pk_fma
            v2f e;
            e.x = __builtin_amdgcn_exp2f(x.x);
            e.y = __builtin_amdgcn_exp2f(x.y);
            e = e + (v2f)(1.0f);                        // pk_add
            v2f r;
            r.x = __builtin_amdgcn_rcpf(e.x);
            r.y = __builtin_amdgcn_rcpf(e.y);
            acc = r * cx[4] + acc;                      // pk_fma
        }
    }

    // Gamma half-tile -> LDS. Gs[(j-jh*16)*32 + k]; (t>>4)*32 + (t&15)*2 == 2t.
    const float bias = cc[0];
    v2f res = acc + (v2f)(bias);
    *((v2f*)(Gs + 2 * t)) = res;

    // ---- Ricci phase: 2 waves, 2 h-units/thread, packed FMA ----
    float wA[33], wB[33];
    float rbvA = 0.0f, rbvB = 0.0f, woA = 0.0f, woB = 0.0f;
    if (t < 128) {
        #pragma unroll
        for (int f = 0; f < 33; ++f) {
            wA[f] = rw1[(32 + f) * 256 + t];
            wB[f] = rw1[(32 + f) * 256 + t + 128];
        }
        rbvA = rbase[b * 256 + t];
        rbvB = rbase[b * 256 + t + 128];
        woA  = rw2[t];
        woB  = rw2[t + 128];
    }
    __syncthreads();

    const float rbias = rb2[0];
    const float* __restrict__ Mrow = Mb + i * 32 + jh * 16;

    if (t < 128) {
        const int wid  = t >> 6;        // 0 or 1
        const int lane = t & 63;

        #pragma unroll 2
        for (int jp = 0; jp < 8; ++jp) {
            float pp[2];
            #pragma unroll
            for (int s = 0; s < 2; ++s) {
                const int jj = jp * 2 + s;
                const float m0 = Mrow[jj];
                v2f hAv = (v2f)(0.0f), hBv = (v2f)(0.0f);
                #pragma unroll
                for (int k4 = 0; k4 < 8; ++k4) {
                    const float4 g = ((const float4*)Gs)[jj * 8 + k4];  // LDS broadcast
                    v2f glo; glo.x = g.x; glo.y = g.y;
                    v2f ghi; ghi.x = g.z; ghi.y = g.w;
                    v2f wloA; wloA.x = wA[k4 * 4 + 1]; wloA.y = wA[k4 * 4 + 2];
                    v2f whiA; whiA.x = wA[k4 * 4 + 3]; whiA.y = wA[k4 * 4 + 4];
                    v2f wloB; wloB.x = wB[k4 * 4 + 1]; wloB.y = wB[k4 * 4 + 2];
                    v2f whiB; whiB.x = wB[k4 * 4 + 3]; whiB.y = wB[k4 * 4 + 4];
                    hAv = glo * wloA + hAv;             // pk_fma
                    hAv = ghi * whiA + hAv;
                    hBv = glo * wloB + hBv;
                    hBv = ghi * whiB + hBv;
                }
                const float hidA = fmaf(m0, wA[0], rbvA) + (hAv.x + hAv.y);
                const float hidB = fmaf(m0, wB[0], rbvB) + (hBv.x + hBv.y);
                pp[s] = fmaxf(hidA, 0.0f) * woA + fmaxf(hidB, 0.0f) * woB;
            }
            const float t0 = pp[0] + __shfl_xor(pp[0], 1);
            const float t1 = pp[1] + __shfl_xor(pp[1], 1);
            float z = (lane & 1) ? t1 : t0;
            #pragma unroll
            for (int off = 2; off < 64; off <<= 1) z += __shfl_xor(z, off);
            if (lane < 2) red[wid][jp * 2 + lane] = z;
        }
    }
    __syncthreads();
    if (t < 16)
        out[((b * 32 + i) * 32) + jh * 16 + t] = red[0][t] + red[1][t] + rbias;
}

extern "C" void kernel_launch(void* const* d_in, const int* in_sizes, int n_in,
                              void* d_out, int out_size, void* d_ws, size_t ws_size,
                              hipStream_t stream) {
    const float* points = (const float*)d_in[0];
    const float* mw1 = (const float*)d_in[1];
    const float* mb1 = (const float*)d_in[2];
    const float* mw2 = (const float*)d_in[3];
    const float* mb2 = (const float*)d_in[4];
    const float* cw1 = (const float*)d_in[5];
    const float* cb1 = (const float*)d_in[6];
    const float* cw2 = (const float*)d_in[7];
    const float* cb2 = (const float*)d_in[8];
    const float* rw1 = (const float*)d_in[9];
    const float* rb1 = (const float*)d_in[10];
    const float* rw2 = (const float*)d_in[11];
    const float* rb2 = (const float*)d_in[12];
    float* out = (float*)d_out;

    char* ws = (char*)d_ws;
    float* metric = (float*)(ws);                  // 32*1024 f32 = 128 KB @ 0
    v8f*   cpkT   = (v8f*)(ws + 131072);           // 32*96*32 B = 96 KB
    v8f*   cpkX   = (v8f*)(ws + 229376);           // 32*32*32 B = 32 KB
    float* rbase  = (float*)(ws + 262144);         // 32 KB
    float* cc     = (float*)(ws + 294912);         // 1 f32 (+pad)

    setup_kernel<<<256, 256, 0, stream>>>(points, mw1, mb1, mw2, mb2,
                                          cw1, cb1, cw2, cb2, rw1, rb1,
                                          metric, cpkT, cpkX, rbase, cc);
    fused_kernel<<<2048, 256, 0, stream>>>(metric, cpkT, cpkX, cc,
                                           rbase, rw1, rw2, rb2, out);
}